// Round 6
// baseline (166.395 us; speedup 1.0000x reference)
//
#include <hip/hip_runtime.h>
#include <hip/hip_bf16.h>
#include <math.h>

#define N_TOKENS 8192
#define DIM      512
#define N_TOOLS  50
#define PARAM_DIM 256
#define N_ROWBLK (N_TOKENS / 64)   // 128 (64-token histogram granules)
#define MAX_BATCHES 128            // BM=128 batches: <= 50 + 64 = 114
#define LDSS 72   // LDS inner stride in bf16 elems (144 B -> 2-way bank aliasing max, free)

typedef float  f32x4 __attribute__((ext_vector_type(4)));
typedef short  s16x8 __attribute__((ext_vector_type(8)));
typedef short  s16x4 __attribute__((ext_vector_type(4)));

// ---- workspace layout (ints) ----
#define WS_IDX     0        // 8192  token -> expert
#define WS_HIST    8192     // 128*50 per-rowblock histograms
#define WS_PHIST   14592    // 128*50 exclusive block-prefix per expert
#define WS_OFFSETS 20992    // 64
#define WS_COUNTS  21056    // 64
#define WS_ORDER   21120    // 8192
#define WS_BE      29312    // 128
#define WS_BM0     29504    // 128
#define WS_NB      29696    // 1
#define WS_XH      32768    // 8192*512 bf16 = 2,097,152 ints
#define WS_XL      2130944  // 8192*512 bf16

__device__ inline float bf2f(short s) {
    return __uint_as_float(((unsigned)(unsigned short)s) << 16);
}

__device__ inline s16x4 pk4(float a, float b, float c, float d) {
    __hip_bfloat162 p0 = __float22bfloat162_rn(make_float2(a, b));
    __hip_bfloat162 p1 = __float22bfloat162_rn(make_float2(c, d));
    union { __hip_bfloat162 h; short2 s; } u0, u1;
    u0.h = p0; u1.h = p1;
    s16x4 r; r[0] = u0.s.x; r[1] = u0.s.y; r[2] = u1.s.x; r[3] = u1.s.y;
    return r;
}

// ---------------- pre-convert x to bf16 hi + lo ----------------
__global__ __launch_bounds__(256) void cvt_x_kernel(const float* __restrict__ x,
                                                    short* __restrict__ xh,
                                                    short* __restrict__ xl) {
    size_t i = (size_t)(blockIdx.x * 256 + threadIdx.x) * 4;
    float4 v = *(const float4*)&x[i];
    s16x4 h = pk4(v.x, v.y, v.z, v.w);
    s16x4 l = pk4(v.x - bf2f(h[0]), v.y - bf2f(h[1]),
                  v.z - bf2f(h[2]), v.w - bf2f(h[3]));
    *(s16x4*)&xh[i] = h;
    *(s16x4*)&xl[i] = l;
}

// ---------------- logits + softmax + argmax + histogram ----------------
// grid 128, block 256 (4 waves). BM=64, N tile 64 (50 valid), split-bf16 (3 MFMAs).
__global__ __launch_bounds__(256) void logits_mfma(const short* __restrict__ xh,
                                                   const short* __restrict__ xl,
                                                   const float* __restrict__ rw,
                                                   const float* __restrict__ rb,
                                                   float* __restrict__ probs,
                                                   float* __restrict__ out_idx,
                                                   int* __restrict__ idx_i,
                                                   int* __restrict__ hist) {
    int r0 = blockIdx.x * 64;

    __shared__ short As[64 * LDSS];
    __shared__ short Al[64 * LDSS];
    __shared__ short Bs[64 * LDSS];
    __shared__ short Bl[64 * LDSS];
    __shared__ int rowcol[64];

    int tid = threadIdx.x;
    int wv = tid >> 6;
    int lane = tid & 63;
    int fm = lane & 15;
    int q = lane >> 4;

    int ar0 = tid >> 3, ag = tid & 7;
    int ar1 = ar0 + 32;
    const short* aptr0  = xh + (size_t)(r0 + ar0) * DIM + ag * 8;
    const short* aptr1  = xh + (size_t)(r0 + ar1) * DIM + ag * 8;
    const short* alptr0 = xl + (size_t)(r0 + ar0) * DIM + ag * 8;
    const short* alptr1 = xl + (size_t)(r0 + ar1) * DIM + ag * 8;
    int bc[4], bg[4];
    const float* bptr[4];
#pragma unroll
    for (int i = 0; i < 4; ++i) {
        int u = i * 256 + tid;
        bc[i] = u >> 4; bg[i] = u & 15;
        bptr[i] = rw + (size_t)bc[i] * DIM + bg[i] * 4;
    }

    f32x4 acc[4] = {{0.f, 0.f, 0.f, 0.f}, {0.f, 0.f, 0.f, 0.f},
                    {0.f, 0.f, 0.f, 0.f}, {0.f, 0.f, 0.f, 0.f}};

    s16x8 apre0 = *(const s16x8*)aptr0;
    s16x8 apre1 = *(const s16x8*)aptr1;
    s16x8 alpre0 = *(const s16x8*)alptr0;
    s16x8 alpre1 = *(const s16x8*)alptr1;
    float4 bpre[4];
#pragma unroll
    for (int i = 0; i < 4; ++i) {
        float4 v = {0.f, 0.f, 0.f, 0.f};
        if (bc[i] < N_TOOLS) v = *(const float4*)bptr[i];
        bpre[i] = v;
    }

    for (int k0 = 0; k0 < DIM; k0 += 64) {
        *(s16x8*)&As[ar0 * LDSS + ag * 8] = apre0;
        *(s16x8*)&As[ar1 * LDSS + ag * 8] = apre1;
        *(s16x8*)&Al[ar0 * LDSS + ag * 8] = alpre0;
        *(s16x8*)&Al[ar1 * LDSS + ag * 8] = alpre1;
#pragma unroll
        for (int i = 0; i < 4; ++i) {
            float4 v = bpre[i];
            s16x4 h = pk4(v.x, v.y, v.z, v.w);
            *(s16x4*)&Bs[bc[i] * LDSS + bg[i] * 4] = h;
            s16x4 l = pk4(v.x - bf2f(h[0]), v.y - bf2f(h[1]),
                          v.z - bf2f(h[2]), v.w - bf2f(h[3]));
            *(s16x4*)&Bl[bc[i] * LDSS + bg[i] * 4] = l;
        }
        __syncthreads();

        int kn = k0 + 64;
        if (kn < DIM) {
            apre0 = *(const s16x8*)(aptr0 + kn);
            apre1 = *(const s16x8*)(aptr1 + kn);
            alpre0 = *(const s16x8*)(alptr0 + kn);
            alpre1 = *(const s16x8*)(alptr1 + kn);
#pragma unroll
            for (int i = 0; i < 4; ++i) {
                float4 v = {0.f, 0.f, 0.f, 0.f};
                if (bc[i] < N_TOOLS) v = *(const float4*)(bptr[i] + kn);
                bpre[i] = v;
            }
        }

#pragma unroll
        for (int kk = 0; kk < 64; kk += 32) {
            int ao = (wv * 16 + fm) * LDSS + kk + q * 8;
            s16x8 a  = *(const s16x8*)&As[ao];
            s16x8 al = *(const s16x8*)&Al[ao];
#pragma unroll
            for (int n = 0; n < 4; ++n) {
                int bo = (n * 16 + fm) * LDSS + kk + q * 8;
                s16x8 b  = *(const s16x8*)&Bs[bo];
                s16x8 bl = *(const s16x8*)&Bl[bo];
                acc[n] = __builtin_amdgcn_mfma_f32_16x16x32_bf16(a,  b,  acc[n], 0, 0, 0);
                acc[n] = __builtin_amdgcn_mfma_f32_16x16x32_bf16(a,  bl, acc[n], 0, 0, 0);
                acc[n] = __builtin_amdgcn_mfma_f32_16x16x32_bf16(al, b,  acc[n], 0, 0, 0);
            }
        }
        __syncthreads();
    }

    float rbv[4];
#pragma unroll
    for (int n = 0; n < 4; ++n) {
        int c = n * 16 + fm;
        rbv[n] = (c < N_TOOLS) ? rb[c] : 0.f;
    }
#pragma unroll
    for (int rr = 0; rr < 4; ++rr) {
        int row_l = wv * 16 + q * 4 + rr;
        int row = r0 + row_l;
        float v[4];
        float vmax = -INFINITY; int vcol = N_TOOLS;
#pragma unroll
        for (int n = 0; n < 4; ++n) {
            int c = n * 16 + fm;
            v[n] = acc[n][rr] + rbv[n];
            if (c < N_TOOLS && v[n] > vmax) { vmax = v[n]; vcol = c; }
        }
#pragma unroll
        for (int s = 1; s < 16; s <<= 1) {
            float om = __shfl_xor(vmax, s, 64);
            int   oc = __shfl_xor(vcol, s, 64);
            if (om > vmax || (om == vmax && oc < vcol)) { vmax = om; vcol = oc; }
        }
        float e[4]; float esum = 0.f;
#pragma unroll
        for (int n = 0; n < 4; ++n) {
            int c = n * 16 + fm;
            e[n] = (c < N_TOOLS) ? expf(v[n] - vmax) : 0.f;
            esum += e[n];
        }
#pragma unroll
        for (int s = 1; s < 16; s <<= 1) esum += __shfl_xor(esum, s, 64);
        float inv = 1.f / esum;
#pragma unroll
        for (int n = 0; n < 4; ++n) {
            int c = n * 16 + fm;
            if (c < N_TOOLS) probs[(size_t)row * N_TOOLS + c] = e[n] * inv;
        }
        if (fm == 0) {
            out_idx[row] = (float)vcol;
            idx_i[row] = vcol;
            rowcol[row_l] = vcol;
        }
    }
    __syncthreads();
    if (wv == 0) {
        int myc = rowcol[lane];
        int cnt = 0;
        for (int e2 = 0; e2 < N_TOOLS; ++e2) {
            unsigned long long m = __ballot(myc == e2);
            if (lane == e2) cnt = __popcll(m);
        }
        if (lane < N_TOOLS) hist[blockIdx.x * N_TOOLS + lane] = cnt;
    }
}

// ---------------- params: bf16 MFMA GEMM, BM=128 BN=128 BK=64 ----------------
// grid (2, 64), block 256 (4 waves). Wave w: rows [w*32, w*32+32) x 128 cols.
__global__ __launch_bounds__(256) void params_mfma(const short* __restrict__ xh,
                                                   const float* __restrict__ pw,
                                                   const float* __restrict__ pb,
                                                   float* __restrict__ out) {
    int r0 = blockIdx.y * 128;
    int c0 = blockIdx.x * 128;

    __shared__ short As[128 * LDSS];
    __shared__ short Bs[128 * LDSS];

    int tid = threadIdx.x;
    int wv = tid >> 6;
    int lane = tid & 63;
    int fm = lane & 15;
    int q = lane >> 4;

    // A: 128 rows x 64 k bf16; 4 granules/thread (rows tid>>3 + 32i, g = tid&7)
    int arb = tid >> 3, ag = tid & 7;
    const short* aptr[4];
#pragma unroll
    for (int i = 0; i < 4; ++i)
        aptr[i] = xh + (size_t)(r0 + arb + 32 * i) * DIM + ag * 8;
    // B: 128 cols x 64 k fp32; 8 granules/thread (cols tid>>4 + 16i, g = tid&15)
    int bcb = tid >> 4, bg = tid & 15;
    const float* bptr[8];
#pragma unroll
    for (int i = 0; i < 8; ++i)
        bptr[i] = pw + (size_t)(c0 + bcb + 16 * i) * DIM + bg * 4;

    f32x4 acc[2][8];
#pragma unroll
    for (int m = 0; m < 2; ++m)
#pragma unroll
        for (int n = 0; n < 8; ++n) acc[m][n] = {0.f, 0.f, 0.f, 0.f};

    s16x8 apre[4];
    float4 bpre[8];
#pragma unroll
    for (int i = 0; i < 4; ++i) apre[i] = *(const s16x8*)aptr[i];
#pragma unroll
    for (int i = 0; i < 8; ++i) bpre[i] = *(const float4*)bptr[i];

    for (int k0 = 0; k0 < DIM; k0 += 64) {
#pragma unroll
        for (int i = 0; i < 4; ++i)
            *(s16x8*)&As[(arb + 32 * i) * LDSS + ag * 8] = apre[i];
#pragma unroll
        for (int i = 0; i < 8; ++i) {
            float4 v = bpre[i];
            *(s16x4*)&Bs[(bcb + 16 * i) * LDSS + bg * 4] = pk4(v.x, v.y, v.z, v.w);
        }
        __syncthreads();

        int kn = k0 + 64;
        if (kn < DIM) {
#pragma unroll
            for (int i = 0; i < 4; ++i) apre[i] = *(const s16x8*)(aptr[i] + kn);
#pragma unroll
            for (int i = 0; i < 8; ++i) bpre[i] = *(const float4*)(bptr[i] + kn);
        }

#pragma unroll
        for (int kk = 0; kk < 64; kk += 32) {
            s16x8 a[2];
#pragma unroll
            for (int m = 0; m < 2; ++m)
                a[m] = *(const s16x8*)&As[(wv * 32 + m * 16 + fm) * LDSS + kk + q * 8];
#pragma unroll
            for (int n = 0; n < 8; ++n) {
                s16x8 b = *(const s16x8*)&Bs[(n * 16 + fm) * LDSS + kk + q * 8];
#pragma unroll
                for (int m = 0; m < 2; ++m)
                    acc[m][n] = __builtin_amdgcn_mfma_f32_16x16x32_bf16(a[m], b, acc[m][n], 0, 0, 0);
            }
        }
        __syncthreads();
    }

    float bias[8];
#pragma unroll
    for (int n = 0; n < 8; ++n) bias[n] = pb[c0 + n * 16 + fm];

#pragma unroll
    for (int m = 0; m < 2; ++m)
#pragma unroll
        for (int r = 0; r < 4; ++r) {
            int row = r0 + wv * 32 + m * 16 + q * 4 + r;
            float* op = out + (size_t)row * PARAM_DIM + c0;
#pragma unroll
            for (int n = 0; n < 8; ++n) op[n * 16 + fm] = acc[m][n][r] + bias[n];
        }
}

// ---------------- fused scan: per-expert block-prefix + offsets + batch table ----------------
// single block, 1024 threads (16 waves)
__global__ __launch_bounds__(1024) void scan_all(const int* __restrict__ hist,
                                                 int* __restrict__ phist,
                                                 int* __restrict__ counts,
                                                 int* __restrict__ offsets,
                                                 int* __restrict__ batch_e,
                                                 int* __restrict__ batch_m0,
                                                 int* __restrict__ nb_out) {
    __shared__ int cnt_s[64];
    int l = threadIdx.x & 63;
    int w = threadIdx.x >> 6;   // 16 waves

    for (int e = w; e < N_TOOLS; e += 16) {
        int v0 = hist[l * N_TOOLS + e];
        int v1 = hist[(64 + l) * N_TOOLS + e];
        int s0 = v0;
#pragma unroll
        for (int s = 1; s < 64; s <<= 1) {
            int t = __shfl_up(s0, s, 64);
            if (l >= s) s0 += t;
        }
        int tot0 = __shfl(s0, 63, 64);
        int s1 = v1;
#pragma unroll
        for (int s = 1; s < 64; s <<= 1) {
            int t = __shfl_up(s1, s, 64);
            if (l >= s) s1 += t;
        }
        s1 += tot0;
        phist[l * N_TOOLS + e] = s0 - v0;
        phist[(64 + l) * N_TOOLS + e] = s1 - v1;
        if (l == 63) cnt_s[e] = s1;
    }
    __syncthreads();

    if (w == 0) {
        int c = (l < N_TOOLS) ? cnt_s[l] : 0;
        int pre = c;
#pragma unroll
        for (int s = 1; s < 64; s <<= 1) {
            int v = __shfl_up(pre, s, 64);
            if (l >= s) pre += v;
        }
        if (l < N_TOOLS) { offsets[l] = pre - c; counts[l] = c; }

        int nb_i = (l < N_TOOLS) ? (c + 127) >> 7 : 0;
        int pre2 = nb_i;
#pragma unroll
        for (int s = 1; s < 64; s <<= 1) {
            int v = __shfl_up(pre2, s, 64);
            if (l >= s) pre2 += v;
        }
        int bstart = pre2 - nb_i;
        for (int b = 0; b < nb_i; ++b) {
            batch_e[bstart + b] = l;
            batch_m0[bstart + b] = b * 128;
        }
        if (l == 63) nb_out[0] = pre2;
    }
}

// ---------------- reorder: deterministic slot per token (no atomics) ----------------
__global__ void reorder_kernel(const int* __restrict__ idx_i,
                               const int* __restrict__ offsets,
                               const int* __restrict__ phist,
                               int* __restrict__ order) {
    int b = blockIdx.x;
    int lane = threadIdx.x;
    int t = b * 64 + lane;
    int e = idx_i[t];
    unsigned long long lt = (1ull << lane) - 1ull;
    int rank = 0;
    for (int ex = 0; ex < N_TOOLS; ++ex) {
        unsigned long long m = __ballot(e == ex);
        if (e == ex) rank = __popcll(m & lt);
    }
    order[offsets[e] + phist[b * N_TOOLS + e] + rank] = t;
}

// ---------------- adapted: grouped bf16 MFMA GEMM, BM=128 BN=128 BK=64 ----------------
// grid (4, MAX_BATCHES), block 256 (4 waves). Wave w: rows [w*32, w*32+32) x 128 cols.
__global__ __launch_bounds__(256) void adapted_mfma(const short* __restrict__ xh,
                                                    const float* __restrict__ ew,
                                                    const float* __restrict__ eb,
                                                    const int* __restrict__ order,
                                                    const int* __restrict__ batch_e,
                                                    const int* __restrict__ batch_m0,
                                                    const int* __restrict__ nb_ptr,
                                                    const int* __restrict__ offsets,
                                                    const int* __restrict__ counts,
                                                    float* __restrict__ out) {
    int b = blockIdx.y;
    if (b >= nb_ptr[0]) return;
    int e = batch_e[b];
    int m0 = batch_m0[b];
    int c0 = blockIdx.x * 128;
    int start = offsets[e] + m0;
    int len = counts[e] - m0;
    if (len > 128) len = 128;

    __shared__ short As[128 * LDSS];
    __shared__ short Bs[128 * LDSS];
    __shared__ int toks[128];

    int tid = threadIdx.x;
    if (tid < 128) toks[tid] = (tid < len) ? order[start + tid] : -1;
    __syncthreads();

    int wv = tid >> 6;
    int lane = tid & 63;
    int fm = lane & 15;
    int q = lane >> 4;

    const float* We = ew + (size_t)e * DIM * DIM;

    // A: 4 granules/thread (rows tid>>3 + 32i, g = tid&7), gathered by toks
    int arb = tid >> 3, ag = tid & 7;
    const short* aptr[4];
#pragma unroll
    for (int i = 0; i < 4; ++i) {
        int tok = toks[arb + 32 * i];
        aptr[i] = (tok >= 0) ? xh + (size_t)tok * DIM + ag * 8 : nullptr;
    }
    // B: 8 granules/thread (cols tid>>4 + 16i, g = tid&15)
    int bcb = tid >> 4, bg = tid & 15;
    const float* bptr[8];
#pragma unroll
    for (int i = 0; i < 8; ++i)
        bptr[i] = We + (size_t)(c0 + bcb + 16 * i) * DIM + bg * 4;

    f32x4 acc[2][8];
#pragma unroll
    for (int m = 0; m < 2; ++m)
#pragma unroll
        for (int n = 0; n < 8; ++n) acc[m][n] = {0.f, 0.f, 0.f, 0.f};

    const s16x8 z8 = {0, 0, 0, 0, 0, 0, 0, 0};
    s16x8 apre[4];
    float4 bpre[8];
#pragma unroll
    for (int i = 0; i < 4; ++i) apre[i] = aptr[i] ? *(const s16x8*)aptr[i] : z8;
#pragma unroll
    for (int i = 0; i < 8; ++i) bpre[i] = *(const float4*)bptr[i];

    for (int k0 = 0; k0 < DIM; k0 += 64) {
#pragma unroll
        for (int i = 0; i < 4; ++i)
            *(s16x8*)&As[(arb + 32 * i) * LDSS + ag * 8] = apre[i];
#pragma unroll
        for (int i = 0; i < 8; ++i) {
            float4 v = bpre[i];
            *(s16x4*)&Bs[(bcb + 16 * i) * LDSS + bg * 4] = pk4(v.x, v.y, v.z, v.w);
        }
        __syncthreads();

        int kn = k0 + 64;
        if (kn < DIM) {
#pragma unroll
            for (int i = 0; i < 4; ++i)
                apre[i] = aptr[i] ? *(const s16x8*)(aptr[i] + kn) : z8;
#pragma unroll
            for (int i = 0; i < 8; ++i) bpre[i] = *(const float4*)(bptr[i] + kn);
        }

#pragma unroll
        for (int kk = 0; kk < 64; kk += 32) {
            s16x8 a[2];
#pragma unroll
            for (int m = 0; m < 2; ++m)
                a[m] = *(const s16x8*)&As[(wv * 32 + m * 16 + fm) * LDSS + kk + q * 8];
#pragma unroll
            for (int n = 0; n < 8; ++n) {
                s16x8 bf = *(const s16x8*)&Bs[(n * 16 + fm) * LDSS + kk + q * 8];
#pragma unroll
                for (int m = 0; m < 2; ++m)
                    acc[m][n] = __builtin_amdgcn_mfma_f32_16x16x32_bf16(a[m], bf, acc[m][n], 0, 0, 0);
            }
        }
        __syncthreads();
    }

    float bias[8];
#pragma unroll
    for (int n = 0; n < 8; ++n) bias[n] = eb[(size_t)e * DIM + c0 + n * 16 + fm];

#pragma unroll
    for (int m = 0; m < 2; ++m)
#pragma unroll
        for (int r = 0; r < 4; ++r) {
            int row = wv * 32 + m * 16 + q * 4 + r;
            int tok = toks[row];
            if (tok < 0) continue;
            float* op = out + (size_t)tok * DIM + c0;
#pragma unroll
            for (int n = 0; n < 8; ++n) op[n * 16 + fm] = acc[m][n][r] + bias[n];
        }
}

extern "C" void kernel_launch(void* const* d_in, const int* in_sizes, int n_in,
                              void* d_out, int out_size, void* d_ws, size_t ws_size,
                              hipStream_t stream) {
    const float* x        = (const float*)d_in[0];
    const float* router_w = (const float*)d_in[1];
    const float* router_b = (const float*)d_in[2];
    const float* expert_w = (const float*)d_in[3];
    const float* expert_b = (const float*)d_in[4];
    const float* param_w  = (const float*)d_in[5];
    const float* param_b  = (const float*)d_in[6];

    float* out = (float*)d_out;
    float* out_idx     = out;                                  // 8192
    float* out_probs   = out + N_TOKENS;                       // 409600
    float* out_adapted = out + N_TOKENS + N_TOKENS * N_TOOLS;  // 4194304
    float* out_params  = out_adapted + (size_t)N_TOKENS * DIM; // 2097152

    int* ws = (int*)d_ws;
    int* ws_idx     = ws + WS_IDX;
    int* ws_hist    = ws + WS_HIST;
    int* ws_phist   = ws + WS_PHIST;
    int* ws_offsets = ws + WS_OFFSETS;
    int* ws_counts  = ws + WS_COUNTS;
    int* ws_order   = ws + WS_ORDER;
    int* ws_be      = ws + WS_BE;
    int* ws_bm0     = ws + WS_BM0;
    int* ws_nb      = ws + WS_NB;
    short* ws_xh    = (short*)(ws + WS_XH);
    short* ws_xl    = (short*)(ws + WS_XL);

    cvt_x_kernel<<<N_TOKENS * DIM / 4 / 256, 256, 0, stream>>>(x, ws_xh, ws_xl);

    logits_mfma<<<N_ROWBLK, 256, 0, stream>>>(ws_xh, ws_xl, router_w, router_b,
                                              out_probs, out_idx, ws_idx, ws_hist);

    scan_all<<<1, 1024, 0, stream>>>(ws_hist, ws_phist, ws_counts, ws_offsets,
                                     ws_be, ws_bm0, ws_nb);

    reorder_kernel<<<N_ROWBLK, 64, 0, stream>>>(ws_idx, ws_offsets, ws_phist, ws_order);

    params_mfma<<<dim3(2, 64), 256, 0, stream>>>(ws_xh, param_w, param_b, out_params);

    adapted_mfma<<<dim3(4, MAX_BATCHES), 256, 0, stream>>>(ws_xh, expert_w, expert_b,
                                                           ws_order, ws_be, ws_bm0, ws_nb,
                                                           ws_offsets, ws_counts, out_adapted);
}

// Round 7
// 159.420 us; speedup vs baseline: 1.0438x; 1.0438x over previous
//
#include <hip/hip_runtime.h>
#include <hip/hip_bf16.h>
#include <math.h>

#define N_TOKENS 8192
#define DIM      512
#define N_TOOLS  50
#define PARAM_DIM 256
#define N_ROWBLK (N_TOKENS / 64)   // 128 (64-token histogram granules)
#define MAX_BATCHES 128            // BM=128 batches: <= 50 + 64 = 114
#define LDSS 72   // LDS inner stride in bf16 elems (144 B -> 2-way bank aliasing max, free)

typedef float  f32x4 __attribute__((ext_vector_type(4)));
typedef short  s16x8 __attribute__((ext_vector_type(8)));
typedef short  s16x4 __attribute__((ext_vector_type(4)));

// ---- workspace layout (ints) ----
#define WS_IDX     0        // 8192  token -> expert
#define WS_HIST    8192     // 128*50 per-rowblock histograms
#define WS_PHIST   14592    // 128*50 exclusive block-prefix per expert
#define WS_OFFSETS 20992    // 64
#define WS_COUNTS  21056    // 64
#define WS_ORDER   21120    // 8192
#define WS_BE      29312    // 128
#define WS_BM0     29504    // 128
#define WS_NB      29696    // 1
#define WS_XH      32768    // 8192*512 bf16 = 2,097,152 ints
#define WS_XL      2130944  // 8192*512 bf16

__device__ inline float bf2f(short s) {
    return __uint_as_float(((unsigned)(unsigned short)s) << 16);
}

__device__ inline s16x4 pk4(float a, float b, float c, float d) {
    __hip_bfloat162 p0 = __float22bfloat162_rn(make_float2(a, b));
    __hip_bfloat162 p1 = __float22bfloat162_rn(make_float2(c, d));
    union { __hip_bfloat162 h; short2 s; } u0, u1;
    u0.h = p0; u1.h = p1;
    s16x4 r; r[0] = u0.s.x; r[1] = u0.s.y; r[2] = u1.s.x; r[3] = u1.s.y;
    return r;
}

// ---------------- pre-convert x to bf16 hi + lo ----------------
__global__ __launch_bounds__(256) void cvt_x_kernel(const float* __restrict__ x,
                                                    short* __restrict__ xh,
                                                    short* __restrict__ xl) {
    size_t i = (size_t)(blockIdx.x * 256 + threadIdx.x) * 4;
    float4 v = *(const float4*)&x[i];
    s16x4 h = pk4(v.x, v.y, v.z, v.w);
    s16x4 l = pk4(v.x - bf2f(h[0]), v.y - bf2f(h[1]),
                  v.z - bf2f(h[2]), v.w - bf2f(h[3]));
    *(s16x4*)&xh[i] = h;
    *(s16x4*)&xl[i] = l;
}

// ---------------- fused head: params (tiles 0-3) + logits/softmax/argmax (tile 4) ----------------
// grid (5, 128), block 256 (4 waves). Tile 64x64, BK=64, register-prefetch pipeline.
__global__ __launch_bounds__(256) void head_mfma(const short* __restrict__ xh,
                                                 const short* __restrict__ xl,
                                                 const float* __restrict__ pw,
                                                 const float* __restrict__ pb,
                                                 const float* __restrict__ rw,
                                                 const float* __restrict__ rb,
                                                 float* __restrict__ out_params,
                                                 float* __restrict__ probs,
                                                 float* __restrict__ out_idx,
                                                 int* __restrict__ idx_i,
                                                 int* __restrict__ hist) {
    int r0 = blockIdx.y * 64;
    bool isl = (blockIdx.x == 4);
    int c0 = isl ? 0 : blockIdx.x * 64;

    __shared__ short As[64 * LDSS];
    __shared__ short Bs[64 * LDSS];
    __shared__ short Al[64 * LDSS];   // lo parts, logits tile only
    __shared__ short Bl[64 * LDSS];
    __shared__ int rowcol[64];

    int tid = threadIdx.x;
    int wv = tid >> 6;
    int lane = tid & 63;
    int fm = lane & 15;
    int q = lane >> 4;

    const float* Bsrc = isl ? rw : pw;

    int ar0 = tid >> 3, ag = tid & 7;
    int ar1 = ar0 + 32;
    const short* aptr0  = xh + (size_t)(r0 + ar0) * DIM + ag * 8;
    const short* aptr1  = xh + (size_t)(r0 + ar1) * DIM + ag * 8;
    const short* alptr0 = xl + (size_t)(r0 + ar0) * DIM + ag * 8;
    const short* alptr1 = xl + (size_t)(r0 + ar1) * DIM + ag * 8;
    int bc[4], bg[4];
    const float* bptr[4];
#pragma unroll
    for (int i = 0; i < 4; ++i) {
        int u = i * 256 + tid;
        bc[i] = u >> 4; bg[i] = u & 15;
        bptr[i] = Bsrc + (size_t)bc[i] * DIM + c0 * (isl ? 0 : 1) * 0 + (size_t)0;
        bptr[i] = Bsrc + (size_t)(c0 + bc[i]) * DIM + bg[i] * 4;
    }

    f32x4 acc[4] = {{0.f, 0.f, 0.f, 0.f}, {0.f, 0.f, 0.f, 0.f},
                    {0.f, 0.f, 0.f, 0.f}, {0.f, 0.f, 0.f, 0.f}};

    s16x8 apre0, apre1, alpre0, alpre1;
    float4 bpre[4];
    apre0 = *(const s16x8*)aptr0;
    apre1 = *(const s16x8*)aptr1;
    if (isl) { alpre0 = *(const s16x8*)alptr0; alpre1 = *(const s16x8*)alptr1; }
#pragma unroll
    for (int i = 0; i < 4; ++i) {
        float4 v = {0.f, 0.f, 0.f, 0.f};
        if (!isl || bc[i] < N_TOOLS) v = *(const float4*)bptr[i];
        bpre[i] = v;
    }

    for (int k0 = 0; k0 < DIM; k0 += 64) {
        *(s16x8*)&As[ar0 * LDSS + ag * 8] = apre0;
        *(s16x8*)&As[ar1 * LDSS + ag * 8] = apre1;
        if (isl) {
            *(s16x8*)&Al[ar0 * LDSS + ag * 8] = alpre0;
            *(s16x8*)&Al[ar1 * LDSS + ag * 8] = alpre1;
        }
#pragma unroll
        for (int i = 0; i < 4; ++i) {
            float4 v = bpre[i];
            s16x4 h = pk4(v.x, v.y, v.z, v.w);
            *(s16x4*)&Bs[bc[i] * LDSS + bg[i] * 4] = h;
            if (isl) {
                s16x4 l = pk4(v.x - bf2f(h[0]), v.y - bf2f(h[1]),
                              v.z - bf2f(h[2]), v.w - bf2f(h[3]));
                *(s16x4*)&Bl[bc[i] * LDSS + bg[i] * 4] = l;
            }
        }
        __syncthreads();

        int kn = k0 + 64;
        if (kn < DIM) {
            apre0 = *(const s16x8*)(aptr0 + kn);
            apre1 = *(const s16x8*)(aptr1 + kn);
            if (isl) {
                alpre0 = *(const s16x8*)(alptr0 + kn);
                alpre1 = *(const s16x8*)(alptr1 + kn);
            }
#pragma unroll
            for (int i = 0; i < 4; ++i) {
                float4 v = {0.f, 0.f, 0.f, 0.f};
                if (!isl || bc[i] < N_TOOLS) v = *(const float4*)(bptr[i] + kn);
                bpre[i] = v;
            }
        }

#pragma unroll
        for (int kk = 0; kk < 64; kk += 32) {
            int ao = (wv * 16 + fm) * LDSS + kk + q * 8;
            s16x8 a = *(const s16x8*)&As[ao];
            if (!isl) {
#pragma unroll
                for (int n = 0; n < 4; ++n) {
                    s16x8 b = *(const s16x8*)&Bs[(n * 16 + fm) * LDSS + kk + q * 8];
                    acc[n] = __builtin_amdgcn_mfma_f32_16x16x32_bf16(a, b, acc[n], 0, 0, 0);
                }
            } else {
                s16x8 al = *(const s16x8*)&Al[ao];
#pragma unroll
                for (int n = 0; n < 4; ++n) {
                    int bo = (n * 16 + fm) * LDSS + kk + q * 8;
                    s16x8 b  = *(const s16x8*)&Bs[bo];
                    s16x8 bl = *(const s16x8*)&Bl[bo];
                    acc[n] = __builtin_amdgcn_mfma_f32_16x16x32_bf16(a,  b,  acc[n], 0, 0, 0);
                    acc[n] = __builtin_amdgcn_mfma_f32_16x16x32_bf16(a,  bl, acc[n], 0, 0, 0);
                    acc[n] = __builtin_amdgcn_mfma_f32_16x16x32_bf16(al, b,  acc[n], 0, 0, 0);
                }
            }
        }
        __syncthreads();
    }

    if (!isl) {
        float bias[4];
#pragma unroll
        for (int n = 0; n < 4; ++n) bias[n] = pb[c0 + n * 16 + fm];
#pragma unroll
        for (int r = 0; r < 4; ++r) {
            int row = r0 + wv * 16 + q * 4 + r;
            float* op = out_params + (size_t)row * PARAM_DIM + c0;
#pragma unroll
            for (int n = 0; n < 4; ++n) op[n * 16 + fm] = acc[n][r] + bias[n];
        }
    } else {
        float rbv[4];
#pragma unroll
        for (int n = 0; n < 4; ++n) {
            int c = n * 16 + fm;
            rbv[n] = (c < N_TOOLS) ? rb[c] : 0.f;
        }
#pragma unroll
        for (int rr = 0; rr < 4; ++rr) {
            int row_l = wv * 16 + q * 4 + rr;
            int row = r0 + row_l;
            float v[4];
            float vmax = -INFINITY; int vcol = N_TOOLS;
#pragma unroll
            for (int n = 0; n < 4; ++n) {
                int c = n * 16 + fm;
                v[n] = acc[n][rr] + rbv[n];
                if (c < N_TOOLS && v[n] > vmax) { vmax = v[n]; vcol = c; }
            }
#pragma unroll
            for (int s = 1; s < 16; s <<= 1) {
                float om = __shfl_xor(vmax, s, 64);
                int   oc = __shfl_xor(vcol, s, 64);
                if (om > vmax || (om == vmax && oc < vcol)) { vmax = om; vcol = oc; }
            }
            float e[4]; float esum = 0.f;
#pragma unroll
            for (int n = 0; n < 4; ++n) {
                int c = n * 16 + fm;
                e[n] = (c < N_TOOLS) ? expf(v[n] - vmax) : 0.f;
                esum += e[n];
            }
#pragma unroll
            for (int s = 1; s < 16; s <<= 1) esum += __shfl_xor(esum, s, 64);
            float inv = 1.f / esum;
#pragma unroll
            for (int n = 0; n < 4; ++n) {
                int c = n * 16 + fm;
                if (c < N_TOOLS) probs[(size_t)row * N_TOOLS + c] = e[n] * inv;
            }
            if (fm == 0) {
                out_idx[row] = (float)vcol;
                idx_i[row] = vcol;
                rowcol[row_l] = vcol;
            }
        }
        __syncthreads();   // isl is block-uniform
        if (wv == 0) {
            int myc = rowcol[lane];
            int cnt = 0;
            for (int e2 = 0; e2 < N_TOOLS; ++e2) {
                unsigned long long m = __ballot(myc == e2);
                if (lane == e2) cnt = __popcll(m);
            }
            if (lane < N_TOOLS) hist[blockIdx.y * N_TOOLS + lane] = cnt;
        }
    }
}

// ---------------- fused scan: per-expert block-prefix + offsets + batch table ----------------
// single block, 1024 threads (16 waves). Batch granule = 128 tokens (BM=128).
__global__ __launch_bounds__(1024) void scan_all(const int* __restrict__ hist,
                                                 int* __restrict__ phist,
                                                 int* __restrict__ counts,
                                                 int* __restrict__ offsets,
                                                 int* __restrict__ batch_e,
                                                 int* __restrict__ batch_m0,
                                                 int* __restrict__ nb_out) {
    __shared__ int cnt_s[64];
    int l = threadIdx.x & 63;
    int w = threadIdx.x >> 6;   // 16 waves

    for (int e = w; e < N_TOOLS; e += 16) {
        int v0 = hist[l * N_TOOLS + e];
        int v1 = hist[(64 + l) * N_TOOLS + e];
        int s0 = v0;
#pragma unroll
        for (int s = 1; s < 64; s <<= 1) {
            int t = __shfl_up(s0, s, 64);
            if (l >= s) s0 += t;
        }
        int tot0 = __shfl(s0, 63, 64);
        int s1 = v1;
#pragma unroll
        for (int s = 1; s < 64; s <<= 1) {
            int t = __shfl_up(s1, s, 64);
            if (l >= s) s1 += t;
        }
        s1 += tot0;
        phist[l * N_TOOLS + e] = s0 - v0;
        phist[(64 + l) * N_TOOLS + e] = s1 - v1;
        if (l == 63) cnt_s[e] = s1;
    }
    __syncthreads();

    if (w == 0) {
        int c = (l < N_TOOLS) ? cnt_s[l] : 0;
        int pre = c;
#pragma unroll
        for (int s = 1; s < 64; s <<= 1) {
            int v = __shfl_up(pre, s, 64);
            if (l >= s) pre += v;
        }
        if (l < N_TOOLS) { offsets[l] = pre - c; counts[l] = c; }

        int nb_i = (l < N_TOOLS) ? (c + 127) >> 7 : 0;
        int pre2 = nb_i;
#pragma unroll
        for (int s = 1; s < 64; s <<= 1) {
            int v = __shfl_up(pre2, s, 64);
            if (l >= s) pre2 += v;
        }
        int bstart = pre2 - nb_i;
        for (int b = 0; b < nb_i; ++b) {
            batch_e[bstart + b] = l;
            batch_m0[bstart + b] = b * 128;
        }
        if (l == 63) nb_out[0] = pre2;
    }
}

// ---------------- reorder: deterministic slot per token (no atomics) ----------------
__global__ void reorder_kernel(const int* __restrict__ idx_i,
                               const int* __restrict__ offsets,
                               const int* __restrict__ phist,
                               int* __restrict__ order) {
    int b = blockIdx.x;
    int lane = threadIdx.x;
    int t = b * 64 + lane;
    int e = idx_i[t];
    unsigned long long lt = (1ull << lane) - 1ull;
    int rank = 0;
    for (int ex = 0; ex < N_TOOLS; ++ex) {
        unsigned long long m = __ballot(e == ex);
        if (e == ex) rank = __popcll(m & lt);
    }
    order[offsets[e] + phist[b * N_TOOLS + e] + rank] = t;
}

// ---------------- adapted: grouped bf16 MFMA GEMM, BM=128 BN=128 BK=64 ----------------
// grid (4, MAX_BATCHES), block 256 (4 waves). Wave w: rows [w*32, w*32+32) x 128 cols.
__global__ __launch_bounds__(256) void adapted_mfma(const short* __restrict__ xh,
                                                    const float* __restrict__ ew,
                                                    const float* __restrict__ eb,
                                                    const int* __restrict__ order,
                                                    const int* __restrict__ batch_e,
                                                    const int* __restrict__ batch_m0,
                                                    const int* __restrict__ nb_ptr,
                                                    const int* __restrict__ offsets,
                                                    const int* __restrict__ counts,
                                                    float* __restrict__ out) {
    int b = blockIdx.y;
    if (b >= nb_ptr[0]) return;
    int e = batch_e[b];
    int m0 = batch_m0[b];
    int c0 = blockIdx.x * 128;
    int start = offsets[e] + m0;
    int len = counts[e] - m0;
    if (len > 128) len = 128;

    __shared__ short As[128 * LDSS];
    __shared__ short Bs[128 * LDSS];
    __shared__ int toks[128];

    int tid = threadIdx.x;
    if (tid < 128) toks[tid] = (tid < len) ? order[start + tid] : -1;
    __syncthreads();

    int wv = tid >> 6;
    int lane = tid & 63;
    int fm = lane & 15;
    int q = lane >> 4;

    const float* We = ew + (size_t)e * DIM * DIM;

    int arb = tid >> 3, ag = tid & 7;
    const short* aptr[4];
#pragma unroll
    for (int i = 0; i < 4; ++i) {
        int tok = toks[arb + 32 * i];
        aptr[i] = (tok >= 0) ? xh + (size_t)tok * DIM + ag * 8 : nullptr;
    }
    int bcb = tid >> 4, bg = tid & 15;
    const float* bptr[8];
#pragma unroll
    for (int i = 0; i < 8; ++i)
        bptr[i] = We + (size_t)(c0 + bcb + 16 * i) * DIM + bg * 4;

    f32x4 acc[2][8];
#pragma unroll
    for (int m = 0; m < 2; ++m)
#pragma unroll
        for (int n = 0; n < 8; ++n) acc[m][n] = {0.f, 0.f, 0.f, 0.f};

    const s16x8 z8 = {0, 0, 0, 0, 0, 0, 0, 0};
    s16x8 apre[4];
    float4 bpre[8];
#pragma unroll
    for (int i = 0; i < 4; ++i) apre[i] = aptr[i] ? *(const s16x8*)aptr[i] : z8;
#pragma unroll
    for (int i = 0; i < 8; ++i) bpre[i] = *(const float4*)bptr[i];

    for (int k0 = 0; k0 < DIM; k0 += 64) {
#pragma unroll
        for (int i = 0; i < 4; ++i)
            *(s16x8*)&As[(arb + 32 * i) * LDSS + ag * 8] = apre[i];
#pragma unroll
        for (int i = 0; i < 8; ++i) {
            float4 v = bpre[i];
            *(s16x4*)&Bs[(bcb + 16 * i) * LDSS + bg * 4] = pk4(v.x, v.y, v.z, v.w);
        }
        __syncthreads();

        int kn = k0 + 64;
        if (kn < DIM) {
#pragma unroll
            for (int i = 0; i < 4; ++i)
                apre[i] = aptr[i] ? *(const s16x8*)(aptr[i] + kn) : z8;
#pragma unroll
            for (int i = 0; i < 8; ++i) bpre[i] = *(const float4*)(bptr[i] + kn);
        }

#pragma unroll
        for (int kk = 0; kk < 64; kk += 32) {
            s16x8 a[2];
#pragma unroll
            for (int m = 0; m < 2; ++m)
                a[m] = *(const s16x8*)&As[(wv * 32 + m * 16 + fm) * LDSS + kk + q * 8];
#pragma unroll
            for (int n = 0; n < 8; ++n) {
                s16x8 bf = *(const s16x8*)&Bs[(n * 16 + fm) * LDSS + kk + q * 8];
#pragma unroll
                for (int m = 0; m < 2; ++m)
                    acc[m][n] = __builtin_amdgcn_mfma_f32_16x16x32_bf16(a[m], bf, acc[m][n], 0, 0, 0);
            }
        }
        __syncthreads();
    }

    float bias[8];
#pragma unroll
    for (int n = 0; n < 8; ++n) bias[n] = eb[(size_t)e * DIM + c0 + n * 16 + fm];

#pragma unroll
    for (int m = 0; m < 2; ++m)
#pragma unroll
        for (int r = 0; r < 4; ++r) {
            int row = wv * 32 + m * 16 + q * 4 + r;
            int tok = toks[row];
            if (tok < 0) continue;
            float* op = out + (size_t)tok * DIM + c0;
#pragma unroll
            for (int n = 0; n < 8; ++n) op[n * 16 + fm] = acc[m][n][r] + bias[n];
        }
}

extern "C" void kernel_launch(void* const* d_in, const int* in_sizes, int n_in,
                              void* d_out, int out_size, void* d_ws, size_t ws_size,
                              hipStream_t stream) {
    const float* x        = (const float*)d_in[0];
    const float* router_w = (const float*)d_in[1];
    const float* router_b = (const float*)d_in[2];
    const float* expert_w = (const float*)d_in[3];
    const float* expert_b = (const float*)d_in[4];
    const float* param_w  = (const float*)d_in[5];
    const float* param_b  = (const float*)d_in[6];

    float* out = (float*)d_out;
    float* out_idx     = out;                                  // 8192
    float* out_probs   = out + N_TOKENS;                       // 409600
    float* out_adapted = out + N_TOKENS + N_TOKENS * N_TOOLS;  // 4194304
    float* out_params  = out_adapted + (size_t)N_TOKENS * DIM; // 2097152

    int* ws = (int*)d_ws;
    int* ws_idx     = ws + WS_IDX;
    int* ws_hist    = ws + WS_HIST;
    int* ws_phist   = ws + WS_PHIST;
    int* ws_offsets = ws + WS_OFFSETS;
    int* ws_counts  = ws + WS_COUNTS;
    int* ws_order   = ws + WS_ORDER;
    int* ws_be      = ws + WS_BE;
    int* ws_bm0     = ws + WS_BM0;
    int* ws_nb      = ws + WS_NB;
    short* ws_xh    = (short*)(ws + WS_XH);
    short* ws_xl    = (short*)(ws + WS_XL);

    cvt_x_kernel<<<N_TOKENS * DIM / 4 / 256, 256, 0, stream>>>(x, ws_xh, ws_xl);

    head_mfma<<<dim3(5, N_ROWBLK), 256, 0, stream>>>(ws_xh, ws_xl, param_w, param_b,
                                                     router_w, router_b,
                                                     out_params, out_probs,
                                                     out_idx, ws_idx, ws_hist);

    scan_all<<<1, 1024, 0, stream>>>(ws_hist, ws_phist, ws_counts, ws_offsets,
                                     ws_be, ws_bm0, ws_nb);

    reorder_kernel<<<N_ROWBLK, 64, 0, stream>>>(ws_idx, ws_offsets, ws_phist, ws_order);

    adapted_mfma<<<dim3(4, MAX_BATCHES), 256, 0, stream>>>(ws_xh, expert_w, expert_b,
                                                           ws_order, ws_be, ws_bm0, ws_nb,
                                                           ws_offsets, ws_counts, out_adapted);
}